// Round 1
// baseline (758.043 us; speedup 1.0000x reference)
//
#include <hip/hip_runtime.h>

#define HID 128

// ---------------- GEMM: H = X @ W^T (fp32, W^T staged in LDS) ----------------
// Block: 256 threads, 32 rows x 128 cols per block, 4x4 per-thread tile.
// K split in two 64-halves so LDS = 32KB (Wt) + 16KB (Xs) = 48KB (3 blocks/CU).
__global__ __launch_bounds__(256) void gemm_kernel(
    const float* __restrict__ X, const float* __restrict__ Wl,
    const float* __restrict__ Wr, float* __restrict__ Hl,
    float* __restrict__ Hr, int n)
{
    const float* __restrict__ W = blockIdx.y ? Wr : Wl;
    float* __restrict__ H       = blockIdx.y ? Hr : Hl;

    __shared__ float Wt[64][HID];   // Wt[kl][j] = W[j][kh*64+kl]
    __shared__ float Xs[32][HID];   // row-major x tile

    const int t    = threadIdx.x;
    const int row0 = blockIdx.x * 32;

    // Stage X tile (coalesced float4 loads, conflict-free LDS stores).
    {
        const int k0 = (t & 31) << 2;
        const int rb = t >> 5;
        #pragma unroll
        for (int rep = 0; rep < 4; ++rep) {
            int r  = rb + (rep << 3);       // 0..31
            int gr = row0 + r;
            float4 v = make_float4(0.f, 0.f, 0.f, 0.f);
            if (gr < n) v = *(const float4*)(X + (size_t)gr * HID + k0);
            *(float4*)&Xs[r][k0] = v;
        }
    }

    const int tr = (t >> 5) << 2;   // row group 0,4,...,28
    const int tc = (t & 31) << 2;   // col 0..124
    float acc[4][4];
    #pragma unroll
    for (int i = 0; i < 4; ++i)
        #pragma unroll
        for (int j = 0; j < 4; ++j) acc[i][j] = 0.f;

    for (int kh = 0; kh < 2; ++kh) {
        __syncthreads();   // Xs ready (kh=0) / previous Wt consumed (kh=1)
        // Stage W transposed: scalar global gathers, coalesced LDS stores.
        {
            const int j0 = (t & 31) << 2;
            const int kb = t >> 5;
            #pragma unroll
            for (int rep = 0; rep < 8; ++rep) {
                int kl = kb + (rep << 3);          // 0..63
                int kg = (kh << 6) + kl;
                float w0 = W[(j0 + 0) * HID + kg];
                float w1 = W[(j0 + 1) * HID + kg];
                float w2 = W[(j0 + 2) * HID + kg];
                float w3 = W[(j0 + 3) * HID + kg];
                *(float4*)&Wt[kl][j0] = make_float4(w0, w1, w2, w3);
            }
        }
        __syncthreads();

        #pragma unroll 4
        for (int k4 = 0; k4 < 16; ++k4) {
            const int kl = k4 << 2;
            const int kg = (kh << 6) + kl;
            float4 xv[4];
            float4 wv[4];
            #pragma unroll
            for (int i = 0; i < 4; ++i)
                xv[i] = *(const float4*)&Xs[tr + i][kg];   // broadcast read
            #pragma unroll
            for (int kk = 0; kk < 4; ++kk)
                wv[kk] = *(const float4*)&Wt[kl + kk][tc]; // conflict-free
            #pragma unroll
            for (int i = 0; i < 4; ++i) {
                const float* xi = (const float*)&xv[i];
                #pragma unroll
                for (int kk = 0; kk < 4; ++kk) {
                    acc[i][0] = fmaf(xi[kk], wv[kk].x, acc[i][0]);
                    acc[i][1] = fmaf(xi[kk], wv[kk].y, acc[i][1]);
                    acc[i][2] = fmaf(xi[kk], wv[kk].z, acc[i][2]);
                    acc[i][3] = fmaf(xi[kk], wv[kk].w, acc[i][3]);
                }
            }
        }
    }

    #pragma unroll
    for (int i = 0; i < 4; ++i) {
        int gr = row0 + tr + i;
        if (gr < n)
            *(float4*)(H + (size_t)gr * HID + tc) =
                make_float4(acc[i][0], acc[i][1], acc[i][2], acc[i][3]);
    }
}

// ---------------- CSR-by-dst build ----------------
__global__ void hist_kernel(const int* __restrict__ dst, int* __restrict__ counts, int e)
{
    int i = blockIdx.x * blockDim.x + threadIdx.x;
    if (i < e) atomicAdd(&counts[dst[i]], 1);
}

__global__ __launch_bounds__(512) void scan1_kernel(
    const int* __restrict__ counts, int* __restrict__ offs,
    int* __restrict__ bsums, int n)
{
    __shared__ int s[512];
    int tid = threadIdx.x;
    int i   = blockIdx.x * 512 + tid;
    int v   = (i < n) ? counts[i] : 0;
    s[tid] = v;
    __syncthreads();
    #pragma unroll
    for (int off = 1; off < 512; off <<= 1) {
        int add = (tid >= off) ? s[tid - off] : 0;
        __syncthreads();
        s[tid] += add;
        __syncthreads();
    }
    if (i < n) offs[i] = s[tid] - v;            // exclusive within block
    if (tid == 511) bsums[blockIdx.x] = s[511]; // block total
}

__global__ __launch_bounds__(512) void scan2_kernel(
    const int* __restrict__ bsums, int* __restrict__ bpref, int nb)
{
    __shared__ int s[512];
    int tid = threadIdx.x;
    int v   = (tid < nb) ? bsums[tid] : 0;
    s[tid] = v;
    __syncthreads();
    #pragma unroll
    for (int off = 1; off < 512; off <<= 1) {
        int add = (tid >= off) ? s[tid - off] : 0;
        __syncthreads();
        s[tid] += add;
        __syncthreads();
    }
    if (tid < nb) bpref[tid] = s[tid] - v;      // exclusive block prefix
}

__global__ void scan3_kernel(int* __restrict__ offs, const int* __restrict__ bpref,
                             int n, int e)
{
    int i = blockIdx.x * blockDim.x + threadIdx.x;
    if (i < n) offs[i] += bpref[i >> 9];
    if (i == 0) offs[n] = e;
}

__global__ void scatter_kernel(const int* __restrict__ dst, const int* __restrict__ offs,
                               int* __restrict__ cursor, int* __restrict__ eids, int e)
{
    int i = blockIdx.x * blockDim.x + threadIdx.x;
    if (i < e) {
        int d   = dst[i];
        int pos = offs[d] + atomicAdd(&cursor[d], 1);
        eids[pos] = i;
    }
}

// ---------------- Fused per-node online-softmax aggregation ----------------
// One wave per dst node. Lane l owns dims {2l, 2l+1}. Single pass over the
// node's edge list with flash-style running (max, denom, acc) rescaling.
__global__ __launch_bounds__(256) void node_kernel(
    const float* __restrict__ hl, const float* __restrict__ hr,
    const float* __restrict__ x,  const float* __restrict__ alpha,
    const int* __restrict__ src,  const int* __restrict__ offs,
    const int* __restrict__ eids, float* __restrict__ out, int n)
{
    int node = blockIdx.x * (blockDim.x >> 6) + (threadIdx.x >> 6);
    int lane = threadIdx.x & 63;
    if (node >= n) return;

    int beg = offs[node];
    int end = offs[node + 1];
    float* orow = out + (size_t)node * HID + (lane << 1);
    if (beg == end) { orow[0] = 0.f; orow[1] = 0.f; return; }

    float2 hr2 = *(const float2*)(hr + (size_t)node * HID + (lane << 1));

    float m = -3.0e38f, denom = 0.f, ax = 0.f, ay = 0.f;
    for (int i = beg; i < end; ++i) {
        int   eid = eids[i];
        int   s   = src[eid];
        float a   = alpha[eid];
        float2 h2 = *(const float2*)(hl + (size_t)s * HID + (lane << 1));
        float2 xv = *(const float2*)(x  + (size_t)s * HID + (lane << 1));

        float z0 = (h2.x + hr2.x) * a;
        float z1 = (h2.y + hr2.y) * a;
        z0 = z0 > 0.f ? z0 : 0.2f * z0;   // leaky_relu, slope 0.2
        z1 = z1 > 0.f ? z1 : 0.2f * z1;
        float p = z0 + z1;
        #pragma unroll
        for (int o = 32; o > 0; o >>= 1) p += __shfl_xor(p, o);
        // p == per-edge score e, identical on all 64 lanes

        if (p > m) {                       // online softmax rescale
            float sc = __expf(m - p);      // first iter: exp(-inf) -> 0
            denom *= sc; ax *= sc; ay *= sc;
            m = p;
        }
        float w = __expf(p - m);
        denom += w;
        ax = fmaf(w, xv.x, ax);
        ay = fmaf(w, xv.y, ay);
    }
    float inv = 1.f / denom;
    orow[0] = ax * inv;
    orow[1] = ay * inv;
}

// ---------------- launcher ----------------
extern "C" void kernel_launch(void* const* d_in, const int* in_sizes, int n_in,
                              void* d_out, int out_size, void* d_ws, size_t ws_size,
                              hipStream_t stream)
{
    const float* x     = (const float*)d_in[0];
    const float* Wl    = (const float*)d_in[1];
    const float* Wr    = (const float*)d_in[2];
    const float* alpha = (const float*)d_in[3];
    const int*   src   = (const int*)d_in[4];
    const int*   dst   = (const int*)d_in[5];
    const int n = in_sizes[0] / HID;   // 100000 nodes
    const int e = in_sizes[4];         // 1600000 edges
    float* out = (float*)d_out;

    // Workspace carve-out (256B aligned): hl, hr, offs, counts, cursor, bsums, bpref, eids
    char* ws = (char*)d_ws;
    size_t off = 0;
    auto carve = [&](size_t bytes) -> void* {
        void* p = ws + off;
        off = (off + bytes + 255) & ~(size_t)255;
        return p;
    };
    float* hl     = (float*)carve((size_t)n * HID * sizeof(float));
    float* hr     = (float*)carve((size_t)n * HID * sizeof(float));
    int*   offs   = (int*)carve((size_t)(n + 1) * sizeof(int));
    int*   counts = (int*)carve((size_t)n * sizeof(int));
    int*   cursor = (int*)carve((size_t)n * sizeof(int));
    int*   bsums  = (int*)carve(512 * sizeof(int));
    int*   bpref  = (int*)carve(512 * sizeof(int));
    int*   eids   = (int*)carve((size_t)e * sizeof(int));

    hipMemsetAsync(counts, 0, (size_t)n * sizeof(int), stream);
    hipMemsetAsync(cursor, 0, (size_t)n * sizeof(int), stream);

    // 1) hl = x @ Wl^T ; hr = x @ Wr^T  (grid.y selects the weight)
    dim3 ggrid((n + 31) / 32, 2);
    gemm_kernel<<<ggrid, 256, 0, stream>>>(x, Wl, Wr, hl, hr, n);

    // 2) CSR by dst
    hist_kernel<<<(e + 255) / 256, 256, 0, stream>>>(dst, counts, e);
    int nb = (n + 511) / 512;
    scan1_kernel<<<nb, 512, 0, stream>>>(counts, offs, bsums, n);
    scan2_kernel<<<1, 512, 0, stream>>>(bsums, bpref, nb);
    scan3_kernel<<<(n + 255) / 256, 256, 0, stream>>>(offs, bpref, n, e);
    scatter_kernel<<<(e + 255) / 256, 256, 0, stream>>>(dst, offs, cursor, eids, e);

    // 3) fused per-node softmax + weighted aggregation
    node_kernel<<<(n + 3) / 4, 256, 0, stream>>>(hl, hr, x, alpha, src, offs, eids, out, n);
}

// Round 2
// 532.740 us; speedup vs baseline: 1.4229x; 1.4229x over previous
//
#include <hip/hip_runtime.h>

#define HID 128

// ---------------- W pre-transpose: Wt[k][j] = W[j][k] ----------------
__global__ __launch_bounds__(256) void transpose_w_kernel(
    const float* __restrict__ Wl, const float* __restrict__ Wr,
    float* __restrict__ Wlt, float* __restrict__ Wrt)
{
    int i = blockIdx.x * 256 + threadIdx.x;          // 0..32767
    const float* in = (i < 16384) ? Wl : Wr;
    float* outp     = (i < 16384) ? Wlt : Wrt;
    int ii = i & 16383;
    int j = ii >> 7, k = ii & 127;
    outp[k * HID + j] = in[j * HID + k];
}

// ---------------- GEMM: H = X @ W^T (fp32, 64x128 tile, 512 thr) ----------------
// Wt_g is the pre-transposed weight (Wt_g[k][j] = W[j][k]), so both staging
// paths are coalesced float4 global loads + contiguous ds_write_b128.
__global__ __launch_bounds__(512) void gemm_kernel(
    const float* __restrict__ X, const float* __restrict__ Wlt,
    const float* __restrict__ Wrt, float* __restrict__ Hl,
    float* __restrict__ Hr, int n)
{
    const float* __restrict__ Wt_g = blockIdx.y ? Wrt : Wlt;
    float* __restrict__ H          = blockIdx.y ? Hr : Hl;

    __shared__ float Wt[64][HID];   // Wt[kl][j] for current k-half
    __shared__ float Xs[64][HID];

    const int t    = threadIdx.x;
    const int row0 = blockIdx.x * 64;

    // Stage X tile: 64x128 floats = 2048 float4, 4 reps of 512 threads.
    #pragma unroll
    for (int rep = 0; rep < 4; ++rep) {
        int idx = rep * 512 + t;
        int r = idx >> 5, k0 = (idx & 31) << 2;
        int gr = row0 + r;
        float4 v = make_float4(0.f, 0.f, 0.f, 0.f);
        if (gr < n) v = *(const float4*)(X + (size_t)gr * HID + k0);
        *(float4*)&Xs[r][k0] = v;
    }

    const int tr = (t >> 5) << 2;   // row group 0,4,...,60
    const int tc = (t & 31) << 2;   // col 0..124
    float acc[4][4];
    #pragma unroll
    for (int i = 0; i < 4; ++i)
        #pragma unroll
        for (int j = 0; j < 4; ++j) acc[i][j] = 0.f;

    for (int kh = 0; kh < 2; ++kh) {
        __syncthreads();   // Xs ready / previous Wt consumed
        // Stage W-half: 64x128 floats, coalesced loads, contiguous LDS stores.
        #pragma unroll
        for (int rep = 0; rep < 4; ++rep) {
            int idx = rep * 512 + t;
            int k = idx >> 5, j0 = (idx & 31) << 2;
            *(float4*)&Wt[k][j0] =
                *(const float4*)(Wt_g + (size_t)((kh << 6) + k) * HID + j0);
        }
        __syncthreads();

        #pragma unroll 4
        for (int k4 = 0; k4 < 16; ++k4) {
            const int kl = k4 << 2;
            const int kg = (kh << 6) + kl;
            float4 xv[4];
            float4 wv[4];
            #pragma unroll
            for (int i = 0; i < 4; ++i)
                xv[i] = *(const float4*)&Xs[tr + i][kg];   // broadcast read
            #pragma unroll
            for (int kk = 0; kk < 4; ++kk)
                wv[kk] = *(const float4*)&Wt[kl + kk][tc]; // conflict-free
            #pragma unroll
            for (int i = 0; i < 4; ++i) {
                const float* xi = (const float*)&xv[i];
                #pragma unroll
                for (int kk = 0; kk < 4; ++kk) {
                    acc[i][0] = fmaf(xi[kk], wv[kk].x, acc[i][0]);
                    acc[i][1] = fmaf(xi[kk], wv[kk].y, acc[i][1]);
                    acc[i][2] = fmaf(xi[kk], wv[kk].z, acc[i][2]);
                    acc[i][3] = fmaf(xi[kk], wv[kk].w, acc[i][3]);
                }
            }
        }
    }

    #pragma unroll
    for (int i = 0; i < 4; ++i) {
        int gr = row0 + tr + i;
        if (gr < n)
            *(float4*)(H + (size_t)gr * HID + tc) =
                make_float4(acc[i][0], acc[i][1], acc[i][2], acc[i][3]);
    }
}

// ---------------- CSR-by-dst build ----------------
__global__ void hist_kernel(const int* __restrict__ dst, int* __restrict__ counts, int e)
{
    int i = blockIdx.x * blockDim.x + threadIdx.x;
    if (i < e) atomicAdd(&counts[dst[i]], 1);
}

__global__ __launch_bounds__(512) void scan1_kernel(
    const int* __restrict__ counts, int* __restrict__ offs,
    int* __restrict__ bsums, int n)
{
    __shared__ int s[512];
    int tid = threadIdx.x;
    int i   = blockIdx.x * 512 + tid;
    int v   = (i < n) ? counts[i] : 0;
    s[tid] = v;
    __syncthreads();
    #pragma unroll
    for (int off = 1; off < 512; off <<= 1) {
        int add = (tid >= off) ? s[tid - off] : 0;
        __syncthreads();
        s[tid] += add;
        __syncthreads();
    }
    if (i < n) offs[i] = s[tid] - v;            // exclusive within block
    if (tid == 511) bsums[blockIdx.x] = s[511]; // block total
}

__global__ __launch_bounds__(512) void scan2_kernel(
    const int* __restrict__ bsums, int* __restrict__ bpref, int nb)
{
    __shared__ int s[512];
    int tid = threadIdx.x;
    int v   = (tid < nb) ? bsums[tid] : 0;
    s[tid] = v;
    __syncthreads();
    #pragma unroll
    for (int off = 1; off < 512; off <<= 1) {
        int add = (tid >= off) ? s[tid - off] : 0;
        __syncthreads();
        s[tid] += add;
        __syncthreads();
    }
    if (tid < nb) bpref[tid] = s[tid] - v;      // exclusive block prefix
}

__global__ void scan3_kernel(int* __restrict__ offs, const int* __restrict__ bpref,
                             int n, int e)
{
    int i = blockIdx.x * blockDim.x + threadIdx.x;
    if (i < n) offs[i] += bpref[i >> 9];
    if (i == 0) offs[n] = e;
}

// Scatter src/alpha into dst-grouped order (removes eids indirection later).
__global__ void scatter_kernel(const int* __restrict__ dst, const int* __restrict__ src,
                               const float* __restrict__ alpha,
                               const int* __restrict__ offs, int* __restrict__ cursor,
                               int* __restrict__ src_s, float* __restrict__ alpha_s, int e)
{
    int i = blockIdx.x * blockDim.x + threadIdx.x;
    if (i < e) {
        int d   = dst[i];
        int pos = offs[d] + atomicAdd(&cursor[d], 1);
        src_s[pos]   = src[i];
        alpha_s[pos] = alpha[i];
    }
}

// ---------------- Fused per-node online-softmax aggregation ----------------
// One wave per dst node; 4 edges processed concurrently (16 lanes per edge,
// 8 dims per lane as 2x float4). Flash-style running (max, denom, acc).
__global__ __launch_bounds__(256) void node_kernel(
    const float* __restrict__ hl, const float* __restrict__ hr,
    const float* __restrict__ x,  const float* __restrict__ alpha_s,
    const int* __restrict__ src_s, const int* __restrict__ offs,
    float* __restrict__ out, int n)
{
    int node = blockIdx.x * 4 + (threadIdx.x >> 6);
    if (node >= n) return;
    int lane = threadIdx.x & 63;
    int sub  = lane >> 4;          // edge slot 0..3
    int sl   = lane & 15;          // dim-slice lane
    int d0   = sl << 2;            // dims [d0,d0+4) and [64+d0,64+d0+4)

    float* orow = out + (size_t)node * HID;
    int beg = offs[node];
    int end = offs[node + 1];
    if (beg == end) {
        if (sub == 0) {
            *(float4*)(orow + d0)      = make_float4(0.f, 0.f, 0.f, 0.f);
            *(float4*)(orow + 64 + d0) = make_float4(0.f, 0.f, 0.f, 0.f);
        }
        return;
    }

    float4 hra = *(const float4*)(hr + (size_t)node * HID + d0);
    float4 hrb = *(const float4*)(hr + (size_t)node * HID + 64 + d0);

    float m = -3.0e38f, denom = 0.f;
    float4 aca = make_float4(0.f, 0.f, 0.f, 0.f);
    float4 acb = make_float4(0.f, 0.f, 0.f, 0.f);

    for (int base = beg; base < end; base += 4) {
        int  e_idx = base + sub;
        bool valid = e_idx < end;
        int   s = valid ? src_s[e_idx]   : 0;
        float a = valid ? alpha_s[e_idx] : 0.f;

        const float* hlr = hl + (size_t)s * HID;
        const float* xr  = x  + (size_t)s * HID;
        float4 ha = *(const float4*)(hlr + d0);
        float4 hb = *(const float4*)(hlr + 64 + d0);
        float4 xa = *(const float4*)(xr + d0);
        float4 xb = *(const float4*)(xr + 64 + d0);

        // Per-edge score: sum over dims of leaky_relu((hl+hr)*a), slope 0.2.
        float p = 0.f, z;
        z = (ha.x + hra.x) * a; p += (z > 0.f ? z : 0.2f * z);
        z = (ha.y + hra.y) * a; p += (z > 0.f ? z : 0.2f * z);
        z = (ha.z + hra.z) * a; p += (z > 0.f ? z : 0.2f * z);
        z = (ha.w + hra.w) * a; p += (z > 0.f ? z : 0.2f * z);
        z = (hb.x + hrb.x) * a; p += (z > 0.f ? z : 0.2f * z);
        z = (hb.y + hrb.y) * a; p += (z > 0.f ? z : 0.2f * z);
        z = (hb.z + hrb.z) * a; p += (z > 0.f ? z : 0.2f * z);
        z = (hb.w + hrb.w) * a; p += (z > 0.f ? z : 0.2f * z);
        p += __shfl_xor(p, 1);
        p += __shfl_xor(p, 2);
        p += __shfl_xor(p, 4);
        p += __shfl_xor(p, 8);      // group-sum (uniform within 16-lane group)
        if (!valid) p = -3.0e38f;

        // Wave-wide max of the 4 group scores.
        float pm = p;
        pm = fmaxf(pm, __shfl_xor(pm, 16));
        pm = fmaxf(pm, __shfl_xor(pm, 32));
        float mn    = fmaxf(m, pm);
        float scale = __expf(m - mn);        // first batch: exp(-huge) = 0
        float w     = __expf(p - mn);        // invalid: exp(-huge) = 0

        denom = denom * scale + w;           // per-sub partial denom
        aca.x = aca.x * scale + w * xa.x;
        aca.y = aca.y * scale + w * xa.y;
        aca.z = aca.z * scale + w * xa.z;
        aca.w = aca.w * scale + w * xa.w;
        acb.x = acb.x * scale + w * xb.x;
        acb.y = acb.y * scale + w * xb.y;
        acb.z = acb.z * scale + w * xb.z;
        acb.w = acb.w * scale + w * xb.w;
        m = mn;
    }

    // Combine the 4 sub-accumulators (all share the same final m).
    denom += __shfl_xor(denom, 16);
    denom += __shfl_xor(denom, 32);
    aca.x += __shfl_xor(aca.x, 16); aca.x += __shfl_xor(aca.x, 32);
    aca.y += __shfl_xor(aca.y, 16); aca.y += __shfl_xor(aca.y, 32);
    aca.z += __shfl_xor(aca.z, 16); aca.z += __shfl_xor(aca.z, 32);
    aca.w += __shfl_xor(aca.w, 16); aca.w += __shfl_xor(aca.w, 32);
    acb.x += __shfl_xor(acb.x, 16); acb.x += __shfl_xor(acb.x, 32);
    acb.y += __shfl_xor(acb.y, 16); acb.y += __shfl_xor(acb.y, 32);
    acb.z += __shfl_xor(acb.z, 16); acb.z += __shfl_xor(acb.z, 32);
    acb.w += __shfl_xor(acb.w, 16); acb.w += __shfl_xor(acb.w, 32);

    if (sub == 0) {
        float inv = 1.f / denom;
        *(float4*)(orow + d0) =
            make_float4(aca.x * inv, aca.y * inv, aca.z * inv, aca.w * inv);
        *(float4*)(orow + 64 + d0) =
            make_float4(acb.x * inv, acb.y * inv, acb.z * inv, acb.w * inv);
    }
}

// ---------------- launcher ----------------
extern "C" void kernel_launch(void* const* d_in, const int* in_sizes, int n_in,
                              void* d_out, int out_size, void* d_ws, size_t ws_size,
                              hipStream_t stream)
{
    const float* x     = (const float*)d_in[0];
    const float* Wl    = (const float*)d_in[1];
    const float* Wr    = (const float*)d_in[2];
    const float* alpha = (const float*)d_in[3];
    const int*   src   = (const int*)d_in[4];
    const int*   dst   = (const int*)d_in[5];
    const int n = in_sizes[0] / HID;   // 100000 nodes
    const int e = in_sizes[4];         // 1600000 edges
    float* out = (float*)d_out;

    // Workspace carve-out (256B aligned)
    char* ws = (char*)d_ws;
    size_t off = 0;
    auto carve = [&](size_t bytes) -> void* {
        void* p = ws + off;
        off = (off + bytes + 255) & ~(size_t)255;
        return p;
    };
    float* hl      = (float*)carve((size_t)n * HID * sizeof(float));
    float* hr      = (float*)carve((size_t)n * HID * sizeof(float));
    int*   offs    = (int*)carve((size_t)(n + 1) * sizeof(int));
    int*   counts  = (int*)carve((size_t)n * sizeof(int));
    int*   cursor  = (int*)carve((size_t)n * sizeof(int));
    int*   bsums   = (int*)carve(512 * sizeof(int));
    int*   bpref   = (int*)carve(512 * sizeof(int));
    int*   src_s   = (int*)carve((size_t)e * sizeof(int));
    float* alpha_s = (float*)carve((size_t)e * sizeof(float));
    float* Wlt     = (float*)carve((size_t)HID * HID * sizeof(float));
    float* Wrt     = (float*)carve((size_t)HID * HID * sizeof(float));

    hipMemsetAsync(counts, 0, (size_t)n * sizeof(int), stream);
    hipMemsetAsync(cursor, 0, (size_t)n * sizeof(int), stream);

    // 0) transpose weights
    transpose_w_kernel<<<128, 256, 0, stream>>>(Wl, Wr, Wlt, Wrt);

    // 1) hl = x @ Wl^T ; hr = x @ Wr^T
    dim3 ggrid((n + 63) / 64, 2);
    gemm_kernel<<<ggrid, 512, 0, stream>>>(x, Wlt, Wrt, hl, hr, n);

    // 2) CSR by dst (+ pre-gathered src/alpha in dst order)
    hist_kernel<<<(e + 255) / 256, 256, 0, stream>>>(dst, counts, e);
    int nb = (n + 511) / 512;
    scan1_kernel<<<nb, 512, 0, stream>>>(counts, offs, bsums, n);
    scan2_kernel<<<1, 512, 0, stream>>>(bsums, bpref, nb);
    scan3_kernel<<<(n + 255) / 256, 256, 0, stream>>>(offs, bpref, n, e);
    scatter_kernel<<<(e + 255) / 256, 256, 0, stream>>>(dst, src, alpha, offs, cursor,
                                                        src_s, alpha_s, e);

    // 3) fused per-node softmax + weighted aggregation
    node_kernel<<<(n + 3) / 4, 256, 0, stream>>>(hl, hr, x, alpha_s, src_s, offs, out, n);
}

// Round 3
// 524.276 us; speedup vs baseline: 1.4459x; 1.0161x over previous
//
#include <hip/hip_runtime.h>

#define HID 128

// ---------------- W pre-transpose: Wt[k][j] = W[j][k] ----------------
__global__ __launch_bounds__(256) void transpose_w_kernel(
    const float* __restrict__ Wl, const float* __restrict__ Wr,
    float* __restrict__ Wlt, float* __restrict__ Wrt)
{
    int i = blockIdx.x * 256 + threadIdx.x;          // 0..32767
    const float* in = (i < 16384) ? Wl : Wr;
    float* outp     = (i < 16384) ? Wlt : Wrt;
    int ii = i & 16383;
    int j = ii >> 7, k = ii & 127;
    outp[k * HID + j] = in[j * HID + k];
}

// ---------------- GEMM: H = X @ W^T (fp32, 64x128 tile, 512 thr) ----------------
__global__ __launch_bounds__(512) void gemm_kernel(
    const float* __restrict__ X, const float* __restrict__ Wlt,
    const float* __restrict__ Wrt, float* __restrict__ Hl,
    float* __restrict__ Hr, int n)
{
    const float* __restrict__ Wt_g = blockIdx.y ? Wrt : Wlt;
    float* __restrict__ H          = blockIdx.y ? Hr : Hl;

    __shared__ float Wt[64][HID];   // Wt[kl][j] for current k-half
    __shared__ float Xs[64][HID];

    const int t    = threadIdx.x;
    const int row0 = blockIdx.x * 64;

    // Stage X tile: 64x128 floats = 2048 float4, 4 reps of 512 threads.
    #pragma unroll
    for (int rep = 0; rep < 4; ++rep) {
        int idx = rep * 512 + t;
        int r = idx >> 5, k0 = (idx & 31) << 2;
        int gr = row0 + r;
        float4 v = make_float4(0.f, 0.f, 0.f, 0.f);
        if (gr < n) v = *(const float4*)(X + (size_t)gr * HID + k0);
        *(float4*)&Xs[r][k0] = v;
    }

    const int tr = (t >> 5) << 2;   // row group 0,4,...,60
    const int tc = (t & 31) << 2;   // col 0..124
    float acc[4][4];
    #pragma unroll
    for (int i = 0; i < 4; ++i)
        #pragma unroll
        for (int j = 0; j < 4; ++j) acc[i][j] = 0.f;

    for (int kh = 0; kh < 2; ++kh) {
        __syncthreads();   // Xs ready / previous Wt consumed
        #pragma unroll
        for (int rep = 0; rep < 4; ++rep) {
            int idx = rep * 512 + t;
            int k = idx >> 5, j0 = (idx & 31) << 2;
            *(float4*)&Wt[k][j0] =
                *(const float4*)(Wt_g + (size_t)((kh << 6) + k) * HID + j0);
        }
        __syncthreads();

        #pragma unroll 4
        for (int k4 = 0; k4 < 16; ++k4) {
            const int kl = k4 << 2;
            const int kg = (kh << 6) + kl;
            float4 xv[4];
            float4 wv[4];
            #pragma unroll
            for (int i = 0; i < 4; ++i)
                xv[i] = *(const float4*)&Xs[tr + i][kg];   // broadcast read
            #pragma unroll
            for (int kk = 0; kk < 4; ++kk)
                wv[kk] = *(const float4*)&Wt[kl + kk][tc]; // conflict-free
            #pragma unroll
            for (int i = 0; i < 4; ++i) {
                const float* xi = (const float*)&xv[i];
                #pragma unroll
                for (int kk = 0; kk < 4; ++kk) {
                    acc[i][0] = fmaf(xi[kk], wv[kk].x, acc[i][0]);
                    acc[i][1] = fmaf(xi[kk], wv[kk].y, acc[i][1]);
                    acc[i][2] = fmaf(xi[kk], wv[kk].z, acc[i][2]);
                    acc[i][3] = fmaf(xi[kk], wv[kk].w, acc[i][3]);
                }
            }
        }
    }

    #pragma unroll
    for (int i = 0; i < 4; ++i) {
        int gr = row0 + tr + i;
        if (gr < n)
            *(float4*)(H + (size_t)gr * HID + tc) =
                make_float4(acc[i][0], acc[i][1], acc[i][2], acc[i][3]);
    }
}

// ---------------- CSR-by-dst build ----------------
__global__ void hist_kernel(const int* __restrict__ dst, int* __restrict__ counts, int e)
{
    int i = blockIdx.x * blockDim.x + threadIdx.x;
    if (i < e) atomicAdd(&counts[dst[i]], 1);
}

__global__ __launch_bounds__(512) void scan1_kernel(
    const int* __restrict__ counts, int* __restrict__ offs,
    int* __restrict__ bsums, int n)
{
    __shared__ int s[512];
    int tid = threadIdx.x;
    int i   = blockIdx.x * 512 + tid;
    int v   = (i < n) ? counts[i] : 0;
    s[tid] = v;
    __syncthreads();
    #pragma unroll
    for (int off = 1; off < 512; off <<= 1) {
        int add = (tid >= off) ? s[tid - off] : 0;
        __syncthreads();
        s[tid] += add;
        __syncthreads();
    }
    if (i < n) offs[i] = s[tid] - v;            // exclusive within block
    if (tid == 511) bsums[blockIdx.x] = s[511]; // block total
}

__global__ __launch_bounds__(512) void scan2_kernel(
    const int* __restrict__ bsums, int* __restrict__ bpref, int nb)
{
    __shared__ int s[512];
    int tid = threadIdx.x;
    int v   = (tid < nb) ? bsums[tid] : 0;
    s[tid] = v;
    __syncthreads();
    #pragma unroll
    for (int off = 1; off < 512; off <<= 1) {
        int add = (tid >= off) ? s[tid - off] : 0;
        __syncthreads();
        s[tid] += add;
        __syncthreads();
    }
    if (tid < nb) bpref[tid] = s[tid] - v;      // exclusive block prefix
}

// Finalize offs and seed cursor with the same value (no extra memset/read later).
__global__ void scan3_kernel(int* __restrict__ offs, const int* __restrict__ bpref,
                             int* __restrict__ cursor, int n, int e)
{
    int i = blockIdx.x * blockDim.x + threadIdx.x;
    if (i < n) {
        int v = offs[i] + bpref[i >> 9];
        offs[i]   = v;
        cursor[i] = v;
    }
    if (i == 0) offs[n] = e;
}

// Scatter fused (src, alpha-bits) records into dst-grouped order.
__global__ void scatter_kernel(const int* __restrict__ dst, const int* __restrict__ src,
                               const float* __restrict__ alpha,
                               int* __restrict__ cursor, int2* __restrict__ edges, int e)
{
    int i = blockIdx.x * blockDim.x + threadIdx.x;
    if (i < e) {
        int pos = atomicAdd(&cursor[dst[i]], 1);
        edges[pos] = make_int2(src[i], __float_as_int(alpha[i]));
    }
}

// ---------------- Fused per-node online-softmax aggregation ----------------
// One wave per dst node; 4 edges per batch (16 lanes/edge, 8 dims/lane).
// 2-deep software pipeline: batch i+1's row gathers + batch i+2's edge
// record load are in flight while batch i computes (shuffles + exp).
__global__ __launch_bounds__(256) void node_kernel(
    const float* __restrict__ hl, const float* __restrict__ hr,
    const float* __restrict__ x,  const int2* __restrict__ edges,
    const int* __restrict__ offs, float* __restrict__ out, int n)
{
    int node = blockIdx.x * 4 + (threadIdx.x >> 6);
    if (node >= n) return;
    int lane = threadIdx.x & 63;
    int sub  = lane >> 4;          // edge slot 0..3
    int d0   = (lane & 15) << 2;   // dims [d0,d0+4) and [64+d0,64+d0+4)

    float* orow = out + (size_t)node * HID;
    int beg = offs[node];
    int end = offs[node + 1];
    if (beg == end) {
        if (sub == 0) {
            *(float4*)(orow + d0)      = make_float4(0.f, 0.f, 0.f, 0.f);
            *(float4*)(orow + 64 + d0) = make_float4(0.f, 0.f, 0.f, 0.f);
        }
        return;
    }

    float4 hra = *(const float4*)(hr + (size_t)node * HID + d0);
    float4 hrb = *(const float4*)(hr + (size_t)node * HID + 64 + d0);

    // ---- pipeline state ----
    int sA; float aA; bool vA;     // current batch edge record
    int sB; float aB; bool vB;     // next batch edge record
    float4 haA, hbA, xaA, xbA;     // current batch rows

    {   // fetch idx A (batch 0)
        int ei = beg + sub;
        vA = ei < end;
        int2 r = vA ? edges[ei] : make_int2(0, 0);
        sA = r.x; aA = __int_as_float(r.y);
    }
    {   // issue rows A (invalid lanes read row 0 -- cheap broadcast, w=0 kills it)
        const float* pl = hl + (size_t)sA * HID;
        const float* px = x  + (size_t)sA * HID;
        haA = *(const float4*)(pl + d0);  hbA = *(const float4*)(pl + 64 + d0);
        xaA = *(const float4*)(px + d0);  xbA = *(const float4*)(px + 64 + d0);
    }
    {   // fetch idx B (batch 1)
        int ei = beg + 4 + sub;
        vB = ei < end;
        int2 r = vB ? edges[ei] : make_int2(0, 0);
        sB = r.x; aB = __int_as_float(r.y);
    }

    float m = -3.0e38f, denom = 0.f;
    float4 aca = make_float4(0.f, 0.f, 0.f, 0.f);
    float4 acb = make_float4(0.f, 0.f, 0.f, 0.f);

    for (int base = beg; base < end; base += 4) {
        // issue rows B (uniform guard: only if another batch exists)
        float4 haB = make_float4(0.f, 0.f, 0.f, 0.f);
        float4 hbB = haB, xaB = haB, xbB = haB;
        bool moreB = (base + 4) < end;
        if (moreB) {
            const float* pl = hl + (size_t)sB * HID;
            const float* px = x  + (size_t)sB * HID;
            haB = *(const float4*)(pl + d0);  hbB = *(const float4*)(pl + 64 + d0);
            xaB = *(const float4*)(px + d0);  xbB = *(const float4*)(px + 64 + d0);
        }
        // prefetch idx C (batch i+2)
        int sC = 0; float aC = 0.f; bool vC = false;
        {
            int ei = base + 8 + sub;
            vC = ei < end;
            int2 r = vC ? edges[ei] : make_int2(0, 0);
            sC = r.x; aC = __int_as_float(r.y);
        }

        // ---- compute batch A (rows B + idx C in flight during this) ----
        float p = 0.f, z;
        z = (haA.x + hra.x) * aA; p += (z > 0.f ? z : 0.2f * z);
        z = (haA.y + hra.y) * aA; p += (z > 0.f ? z : 0.2f * z);
        z = (haA.z + hra.z) * aA; p += (z > 0.f ? z : 0.2f * z);
        z = (haA.w + hra.w) * aA; p += (z > 0.f ? z : 0.2f * z);
        z = (hbA.x + hrb.x) * aA; p += (z > 0.f ? z : 0.2f * z);
        z = (hbA.y + hrb.y) * aA; p += (z > 0.f ? z : 0.2f * z);
        z = (hbA.z + hrb.z) * aA; p += (z > 0.f ? z : 0.2f * z);
        z = (hbA.w + hrb.w) * aA; p += (z > 0.f ? z : 0.2f * z);
        p += __shfl_xor(p, 1);
        p += __shfl_xor(p, 2);
        p += __shfl_xor(p, 4);
        p += __shfl_xor(p, 8);          // per-edge score, uniform in 16-lane group
        if (!vA) p = -3.0e38f;

        float pm = p;
        pm = fmaxf(pm, __shfl_xor(pm, 16));
        pm = fmaxf(pm, __shfl_xor(pm, 32));   // wave-wide batch max
        float mn    = fmaxf(m, pm);
        float scale = __expf(m - mn);         // first batch: exp(-huge) = 0
        float w     = __expf(p - mn);         // invalid: exp(-huge) = 0

        denom = denom * scale + w;
        aca.x = aca.x * scale + w * xaA.x;
        aca.y = aca.y * scale + w * xaA.y;
        aca.z = aca.z * scale + w * xaA.z;
        aca.w = aca.w * scale + w * xaA.w;
        acb.x = acb.x * scale + w * xbA.x;
        acb.y = acb.y * scale + w * xbA.y;
        acb.z = acb.z * scale + w * xbA.z;
        acb.w = acb.w * scale + w * xbA.w;
        m = mn;

        // ---- rotate pipeline registers ----
        sA = sB; aA = aB; vA = vB;
        haA = haB; hbA = hbB; xaA = xaB; xbA = xbB;
        sB = sC; aB = aC; vB = vC;
    }

    // Combine the 4 sub-accumulators (all share the same final m).
    denom += __shfl_xor(denom, 16);
    denom += __shfl_xor(denom, 32);
    aca.x += __shfl_xor(aca.x, 16); aca.x += __shfl_xor(aca.x, 32);
    aca.y += __shfl_xor(aca.y, 16); aca.y += __shfl_xor(aca.y, 32);
    aca.z += __shfl_xor(aca.z, 16); aca.z += __shfl_xor(aca.z, 32);
    aca.w += __shfl_xor(aca.w, 16); aca.w += __shfl_xor(aca.w, 32);
    acb.x += __shfl_xor(acb.x, 16); acb.x += __shfl_xor(acb.x, 32);
    acb.y += __shfl_xor(acb.y, 16); acb.y += __shfl_xor(acb.y, 32);
    acb.z += __shfl_xor(acb.z, 16); acb.z += __shfl_xor(acb.z, 32);
    acb.w += __shfl_xor(acb.w, 16); acb.w += __shfl_xor(acb.w, 32);

    if (sub == 0) {
        float inv = 1.f / denom;
        *(float4*)(orow + d0) =
            make_float4(aca.x * inv, aca.y * inv, aca.z * inv, aca.w * inv);
        *(float4*)(orow + 64 + d0) =
            make_float4(acb.x * inv, acb.y * inv, acb.z * inv, acb.w * inv);
    }
}

// ---------------- launcher ----------------
extern "C" void kernel_launch(void* const* d_in, const int* in_sizes, int n_in,
                              void* d_out, int out_size, void* d_ws, size_t ws_size,
                              hipStream_t stream)
{
    const float* x     = (const float*)d_in[0];
    const float* Wl    = (const float*)d_in[1];
    const float* Wr    = (const float*)d_in[2];
    const float* alpha = (const float*)d_in[3];
    const int*   src   = (const int*)d_in[4];
    const int*   dst   = (const int*)d_in[5];
    const int n = in_sizes[0] / HID;   // 100000 nodes
    const int e = in_sizes[4];         // 1600000 edges
    float* out = (float*)d_out;

    // Workspace carve-out (256B aligned)
    char* ws = (char*)d_ws;
    size_t off = 0;
    auto carve = [&](size_t bytes) -> void* {
        void* p = ws + off;
        off = (off + bytes + 255) & ~(size_t)255;
        return p;
    };
    float* hl      = (float*)carve((size_t)n * HID * sizeof(float));
    float* hr      = (float*)carve((size_t)n * HID * sizeof(float));
    int*   offs    = (int*)carve((size_t)(n + 1) * sizeof(int));
    int*   counts  = (int*)carve((size_t)n * sizeof(int));
    int*   cursor  = (int*)carve((size_t)n * sizeof(int));
    int*   bsums   = (int*)carve(512 * sizeof(int));
    int*   bpref   = (int*)carve(512 * sizeof(int));
    int2*  edges   = (int2*)carve((size_t)e * sizeof(int2));
    float* Wlt     = (float*)carve((size_t)HID * HID * sizeof(float));
    float* Wrt     = (float*)carve((size_t)HID * HID * sizeof(float));

    hipMemsetAsync(counts, 0, (size_t)n * sizeof(int), stream);

    // 0) transpose weights
    transpose_w_kernel<<<128, 256, 0, stream>>>(Wl, Wr, Wlt, Wrt);

    // 1) hl = x @ Wl^T ; hr = x @ Wr^T
    dim3 ggrid((n + 63) / 64, 2);
    gemm_kernel<<<ggrid, 512, 0, stream>>>(x, Wlt, Wrt, hl, hr, n);

    // 2) CSR by dst (+ fused (src, alpha) records in dst order)
    hist_kernel<<<(e + 255) / 256, 256, 0, stream>>>(dst, counts, e);
    int nb = (n + 511) / 512;
    scan1_kernel<<<nb, 512, 0, stream>>>(counts, offs, bsums, n);
    scan2_kernel<<<1, 512, 0, stream>>>(bsums, bpref, nb);
    scan3_kernel<<<(n + 255) / 256, 256, 0, stream>>>(offs, bpref, cursor, n, e);
    scatter_kernel<<<(e + 255) / 256, 256, 0, stream>>>(dst, src, alpha, cursor, edges, e);

    // 3) fused per-node softmax + weighted aggregation
    node_kernel<<<(n + 3) / 4, 256, 0, stream>>>(hl, hr, x, edges, offs, out, n);
}

// Round 4
// 461.434 us; speedup vs baseline: 1.6428x; 1.1362x over previous
//
#include <hip/hip_runtime.h>
#include <hip/hip_fp16.h>

#define HID 128

struct h8 { __half2 a, b, c, d; };   // 16 B = 8 halves
struct h4 { __half2 x, y; };         // 8 B = 4 halves

// ---------------- W pre-transpose: Wt[k][j] = W[j][k] ----------------
__global__ __launch_bounds__(256) void transpose_w_kernel(
    const float* __restrict__ Wl, const float* __restrict__ Wr,
    float* __restrict__ Wlt, float* __restrict__ Wrt)
{
    int i = blockIdx.x * 256 + threadIdx.x;          // 0..32767
    const float* in = (i < 16384) ? Wl : Wr;
    float* outp     = (i < 16384) ? Wlt : Wrt;
    int ii = i & 16383;
    int j = ii >> 7, k = ii & 127;
    outp[k * HID + j] = in[j * HID + k];
}

// ---------------- x -> fp16 rows ----------------
__global__ __launch_bounds__(256) void xhalf_kernel(
    const float* __restrict__ x, h8* __restrict__ xh, int total /* n*16 */)
{
    int i = blockIdx.x * 256 + threadIdx.x;
    if (i >= total) return;
    const float4* p = (const float4*)x + (size_t)i * 2;
    float4 v0 = p[0], v1 = p[1];
    h8 o;
    o.a = __float22half2_rn(make_float2(v0.x, v0.y));
    o.b = __float22half2_rn(make_float2(v0.z, v0.w));
    o.c = __float22half2_rn(make_float2(v1.x, v1.y));
    o.d = __float22half2_rn(make_float2(v1.z, v1.w));
    xh[i] = o;
}

// ---------------- GEMM: H = X @ W^T (fp32 math, fp16 output rows) ----------------
__global__ __launch_bounds__(512) void gemm_kernel(
    const float* __restrict__ X, const float* __restrict__ Wlt,
    const float* __restrict__ Wrt, __half* __restrict__ Hl,
    __half* __restrict__ Hr, int n)
{
    const float* __restrict__ Wt_g = blockIdx.y ? Wrt : Wlt;
    __half* __restrict__ H         = blockIdx.y ? Hr : Hl;

    __shared__ float Wt[64][HID];
    __shared__ float Xs[64][HID];

    const int t    = threadIdx.x;
    const int row0 = blockIdx.x * 64;

    #pragma unroll
    for (int rep = 0; rep < 4; ++rep) {
        int idx = rep * 512 + t;
        int r = idx >> 5, k0 = (idx & 31) << 2;
        int gr = row0 + r;
        float4 v = make_float4(0.f, 0.f, 0.f, 0.f);
        if (gr < n) v = *(const float4*)(X + (size_t)gr * HID + k0);
        *(float4*)&Xs[r][k0] = v;
    }

    const int tr = (t >> 5) << 2;
    const int tc = (t & 31) << 2;
    float acc[4][4];
    #pragma unroll
    for (int i = 0; i < 4; ++i)
        #pragma unroll
        for (int j = 0; j < 4; ++j) acc[i][j] = 0.f;

    for (int kh = 0; kh < 2; ++kh) {
        __syncthreads();
        #pragma unroll
        for (int rep = 0; rep < 4; ++rep) {
            int idx = rep * 512 + t;
            int k = idx >> 5, j0 = (idx & 31) << 2;
            *(float4*)&Wt[k][j0] =
                *(const float4*)(Wt_g + (size_t)((kh << 6) + k) * HID + j0);
        }
        __syncthreads();

        #pragma unroll 4
        for (int k4 = 0; k4 < 16; ++k4) {
            const int kl = k4 << 2;
            const int kg = (kh << 6) + kl;
            float4 xv[4];
            float4 wv[4];
            #pragma unroll
            for (int i = 0; i < 4; ++i)
                xv[i] = *(const float4*)&Xs[tr + i][kg];
            #pragma unroll
            for (int kk = 0; kk < 4; ++kk)
                wv[kk] = *(const float4*)&Wt[kl + kk][tc];
            #pragma unroll
            for (int i = 0; i < 4; ++i) {
                const float* xi = (const float*)&xv[i];
                #pragma unroll
                for (int kk = 0; kk < 4; ++kk) {
                    acc[i][0] = fmaf(xi[kk], wv[kk].x, acc[i][0]);
                    acc[i][1] = fmaf(xi[kk], wv[kk].y, acc[i][1]);
                    acc[i][2] = fmaf(xi[kk], wv[kk].z, acc[i][2]);
                    acc[i][3] = fmaf(xi[kk], wv[kk].w, acc[i][3]);
                }
            }
        }
    }

    #pragma unroll
    for (int i = 0; i < 4; ++i) {
        int gr = row0 + tr + i;
        if (gr < n) {
            h4 hv;
            hv.x = __float22half2_rn(make_float2(acc[i][0], acc[i][1]));
            hv.y = __float22half2_rn(make_float2(acc[i][2], acc[i][3]));
            *(h4*)(H + (size_t)gr * HID + tc) = hv;
        }
    }
}

// ---------------- CSR-by-dst build ----------------
__global__ void hist_kernel(const int* __restrict__ dst, int* __restrict__ counts, int e)
{
    int i = blockIdx.x * blockDim.x + threadIdx.x;
    if (i < e) atomicAdd(&counts[dst[i]], 1);
}

__global__ __launch_bounds__(512) void scan1_kernel(
    const int* __restrict__ counts, int* __restrict__ offs,
    int* __restrict__ bsums, int n)
{
    __shared__ int s[512];
    int tid = threadIdx.x;
    int i   = blockIdx.x * 512 + tid;
    int v   = (i < n) ? counts[i] : 0;
    s[tid] = v;
    __syncthreads();
    #pragma unroll
    for (int off = 1; off < 512; off <<= 1) {
        int add = (tid >= off) ? s[tid - off] : 0;
        __syncthreads();
        s[tid] += add;
        __syncthreads();
    }
    if (i < n) offs[i] = s[tid] - v;
    if (tid == 511) bsums[blockIdx.x] = s[511];
}

__global__ __launch_bounds__(512) void scan2_kernel(
    const int* __restrict__ bsums, int* __restrict__ bpref, int nb)
{
    __shared__ int s[512];
    int tid = threadIdx.x;
    int v   = (tid < nb) ? bsums[tid] : 0;
    s[tid] = v;
    __syncthreads();
    #pragma unroll
    for (int off = 1; off < 512; off <<= 1) {
        int add = (tid >= off) ? s[tid - off] : 0;
        __syncthreads();
        s[tid] += add;
        __syncthreads();
    }
    if (tid < nb) bpref[tid] = s[tid] - v;
}

__global__ void scan3_kernel(int* __restrict__ offs, const int* __restrict__ bpref,
                             int* __restrict__ cursor, int n, int e)
{
    int i = blockIdx.x * blockDim.x + threadIdx.x;
    if (i < n) {
        int v = offs[i] + bpref[i >> 9];
        offs[i]   = v;
        cursor[i] = v;
    }
    if (i == 0) offs[n] = e;
}

__global__ void scatter_kernel(const int* __restrict__ dst, const int* __restrict__ src,
                               const float* __restrict__ alpha,
                               int* __restrict__ cursor, int2* __restrict__ edges, int e)
{
    int i = blockIdx.x * blockDim.x + threadIdx.x;
    if (i < e) {
        int pos = atomicAdd(&cursor[dst[i]], 1);
        edges[pos] = make_int2(src[i], __float_as_int(alpha[i]));
    }
}

// ---------------- Pass 1: per-edge scores + online (max, denom) per node ----
// One wave per node; 4 edges/batch, 16 lanes/edge, 8 dims/lane (one h8 load).
// Writes score into edges[i].y (in place over alpha) and maxdenom[node].
__global__ __launch_bounds__(256) void score_kernel(
    const h8* __restrict__ hl, const h8* __restrict__ hr,
    int2* __restrict__ edges, const int* __restrict__ offs,
    float2* __restrict__ maxdenom, int n)
{
    int node = blockIdx.x * 4 + (threadIdx.x >> 6);
    if (node >= n) return;
    int lane = threadIdx.x & 63;
    int sub  = lane >> 4;
    int sl   = lane & 15;

    int beg = offs[node];
    int end = offs[node + 1];
    if (beg == end) return;

    h8 hv = hr[(size_t)node * 16 + sl];
    float2 h0 = __half22float2(hv.a), h1 = __half22float2(hv.b);
    float2 h2 = __half22float2(hv.c), h3 = __half22float2(hv.d);

    // pipeline: recA(current) / rowA(current) / recB(next)
    int2 recA, recB; bool vA, vB;
    h8 rowA;
    {
        int ei = beg + sub;
        vA = ei < end;
        recA = vA ? edges[ei] : make_int2(0, 0);
    }
    rowA = hl[(size_t)recA.x * 16 + sl];
    {
        int ei = beg + 4 + sub;
        vB = ei < end;
        recB = vB ? edges[ei] : make_int2(0, 0);
    }

    float m = -3.0e38f, den = 0.f;
    for (int base = beg; base < end; base += 4) {
        h8 rowB;
        bool more = (base + 4) < end;
        if (more) rowB = hl[(size_t)recB.x * 16 + sl];
        int2 recC = make_int2(0, 0);
        bool vC = (base + 8 + sub) < end;
        if (vC) recC = edges[base + 8 + sub];

        float a = __int_as_float(recA.y);
        float p = 0.f, z;
        float2 t;
        t = __half22float2(rowA.a);
        z = (t.x + h0.x) * a; p += (z > 0.f ? z : 0.2f * z);
        z = (t.y + h0.y) * a; p += (z > 0.f ? z : 0.2f * z);
        t = __half22float2(rowA.b);
        z = (t.x + h1.x) * a; p += (z > 0.f ? z : 0.2f * z);
        z = (t.y + h1.y) * a; p += (z > 0.f ? z : 0.2f * z);
        t = __half22float2(rowA.c);
        z = (t.x + h2.x) * a; p += (z > 0.f ? z : 0.2f * z);
        z = (t.y + h2.y) * a; p += (z > 0.f ? z : 0.2f * z);
        t = __half22float2(rowA.d);
        z = (t.x + h3.x) * a; p += (z > 0.f ? z : 0.2f * z);
        z = (t.y + h3.y) * a; p += (z > 0.f ? z : 0.2f * z);
        p += __shfl_xor(p, 1);
        p += __shfl_xor(p, 2);
        p += __shfl_xor(p, 4);
        p += __shfl_xor(p, 8);          // per-edge score, uniform in 16-lane group
        if (!vA) p = -3.0e38f;
        if (vA && sl == 0) edges[base + sub].y = __float_as_int(p);  // store score

        float pm = fmaxf(p, __shfl_xor(p, 16));
        pm = fmaxf(pm, __shfl_xor(pm, 32));
        float mn = fmaxf(m, pm);
        float sc = __expf(m - mn);      // first batch: exp(-huge) = 0
        float w  = __expf(p - mn);      // invalid: exp(-huge) = 0
        den = den * sc + w;
        m = mn;

        recA = recB; vA = vB; rowA = rowB;
        recB = recC; vB = vC;
    }

    den += __shfl_xor(den, 16);
    den += __shfl_xor(den, 32);
    if (lane == 0) maxdenom[node] = make_float2(m, 1.f / den);
}

// ---------------- Pass 2: weighted aggregation ----------------
// Hot loop: load (src,score), w=exp(score-m)*inv, gather x_h row, FMA.
__global__ __launch_bounds__(256) void agg_kernel(
    const h8* __restrict__ xh, const int2* __restrict__ edges,
    const int* __restrict__ offs, const float2* __restrict__ maxdenom,
    float* __restrict__ out, int n)
{
    int node = blockIdx.x * 4 + (threadIdx.x >> 6);
    if (node >= n) return;
    int lane = threadIdx.x & 63;
    int sub  = lane >> 4;
    int sl   = lane & 15;

    float* orow = out + (size_t)node * HID + (sl << 3);
    int beg = offs[node];
    int end = offs[node + 1];
    if (beg == end) {
        if (sub == 0) {
            *(float4*)orow       = make_float4(0.f, 0.f, 0.f, 0.f);
            *(float4*)(orow + 4) = make_float4(0.f, 0.f, 0.f, 0.f);
        }
        return;
    }

    float2 md = maxdenom[node];
    const float m = md.x, inv = md.y;

    int2 recA, recB; bool vA, vB;
    h8 rowA;
    {
        int ei = beg + sub;
        vA = ei < end;
        recA = vA ? edges[ei] : make_int2(0, 0);
    }
    rowA = xh[(size_t)recA.x * 16 + sl];
    {
        int ei = beg + 4 + sub;
        vB = ei < end;
        recB = vB ? edges[ei] : make_int2(0, 0);
    }

    float4 aca = make_float4(0.f, 0.f, 0.f, 0.f);
    float4 acb = make_float4(0.f, 0.f, 0.f, 0.f);

    for (int base = beg; base < end; base += 4) {
        h8 rowB;
        bool more = (base + 4) < end;
        if (more) rowB = xh[(size_t)recB.x * 16 + sl];
        int2 recC = make_int2(0, 0);
        bool vC = (base + 8 + sub) < end;
        if (vC) recC = edges[base + 8 + sub];

        float w = vA ? __expf(__int_as_float(recA.y) - m) * inv : 0.f;
        float2 t;
        t = __half22float2(rowA.a);
        aca.x = fmaf(w, t.x, aca.x); aca.y = fmaf(w, t.y, aca.y);
        t = __half22float2(rowA.b);
        aca.z = fmaf(w, t.x, aca.z); aca.w = fmaf(w, t.y, aca.w);
        t = __half22float2(rowA.c);
        acb.x = fmaf(w, t.x, acb.x); acb.y = fmaf(w, t.y, acb.y);
        t = __half22float2(rowA.d);
        acb.z = fmaf(w, t.x, acb.z); acb.w = fmaf(w, t.y, acb.w);

        recA = recB; vA = vB; rowA = rowB;
        recB = recC; vB = vC;
    }

    // combine across the 4 edge slots
    aca.x += __shfl_xor(aca.x, 16); aca.x += __shfl_xor(aca.x, 32);
    aca.y += __shfl_xor(aca.y, 16); aca.y += __shfl_xor(aca.y, 32);
    aca.z += __shfl_xor(aca.z, 16); aca.z += __shfl_xor(aca.z, 32);
    aca.w += __shfl_xor(aca.w, 16); aca.w += __shfl_xor(aca.w, 32);
    acb.x += __shfl_xor(acb.x, 16); acb.x += __shfl_xor(acb.x, 32);
    acb.y += __shfl_xor(acb.y, 16); acb.y += __shfl_xor(acb.y, 32);
    acb.z += __shfl_xor(acb.z, 16); acb.z += __shfl_xor(acb.z, 32);
    acb.w += __shfl_xor(acb.w, 16); acb.w += __shfl_xor(acb.w, 32);

    if (sub == 0) {
        *(float4*)orow       = aca;
        *(float4*)(orow + 4) = acb;
    }
}

// ---------------- launcher ----------------
extern "C" void kernel_launch(void* const* d_in, const int* in_sizes, int n_in,
                              void* d_out, int out_size, void* d_ws, size_t ws_size,
                              hipStream_t stream)
{
    const float* x     = (const float*)d_in[0];
    const float* Wl    = (const float*)d_in[1];
    const float* Wr    = (const float*)d_in[2];
    const float* alpha = (const float*)d_in[3];
    const int*   src   = (const int*)d_in[4];
    const int*   dst   = (const int*)d_in[5];
    const int n = in_sizes[0] / HID;   // 100000 nodes
    const int e = in_sizes[4];         // 1600000 edges
    float* out = (float*)d_out;

    // Workspace carve-out (256B aligned)
    char* ws = (char*)d_ws;
    size_t off = 0;
    auto carve = [&](size_t bytes) -> void* {
        void* p = ws + off;
        off = (off + bytes + 255) & ~(size_t)255;
        return p;
    };
    __half* hl_h    = (__half*)carve((size_t)n * HID * sizeof(__half));
    __half* hr_h    = (__half*)carve((size_t)n * HID * sizeof(__half));
    h8*     xh      = (h8*)carve((size_t)n * HID * sizeof(__half));
    int*    offs    = (int*)carve((size_t)(n + 1) * sizeof(int));
    int*    counts  = (int*)carve((size_t)n * sizeof(int));
    int*    cursor  = (int*)carve((size_t)n * sizeof(int));
    int*    bsums   = (int*)carve(512 * sizeof(int));
    int*    bpref   = (int*)carve(512 * sizeof(int));
    int2*   edges   = (int2*)carve((size_t)e * sizeof(int2));
    float2* maxden  = (float2*)carve((size_t)n * sizeof(float2));
    float*  Wlt     = (float*)carve((size_t)HID * HID * sizeof(float));
    float*  Wrt     = (float*)carve((size_t)HID * HID * sizeof(float));

    hipMemsetAsync(counts, 0, (size_t)n * sizeof(int), stream);

    // 0) transpose weights + fp16 copy of x
    transpose_w_kernel<<<128, 256, 0, stream>>>(Wl, Wr, Wlt, Wrt);
    xhalf_kernel<<<(n * 16 + 255) / 256, 256, 0, stream>>>(x, xh, n * 16);

    // 1) hl = x @ Wl^T ; hr = x @ Wr^T  (fp16 rows out)
    dim3 ggrid((n + 63) / 64, 2);
    gemm_kernel<<<ggrid, 512, 0, stream>>>(x, Wlt, Wrt, hl_h, hr_h, n);

    // 2) CSR by dst (fused (src, alpha) records in dst order)
    hist_kernel<<<(e + 255) / 256, 256, 0, stream>>>(dst, counts, e);
    int nb = (n + 511) / 512;
    scan1_kernel<<<nb, 512, 0, stream>>>(counts, offs, bsums, n);
    scan2_kernel<<<1, 512, 0, stream>>>(bsums, bpref, nb);
    scan3_kernel<<<(n + 255) / 256, 256, 0, stream>>>(offs, bpref, cursor, n, e);
    scatter_kernel<<<(e + 255) / 256, 256, 0, stream>>>(dst, src, alpha, cursor, edges, e);

    // 3) pass 1: scores + (max, 1/denom); pass 2: weighted aggregation
    score_kernel<<<(n + 3) / 4, 256, 0, stream>>>(
        (const h8*)hl_h, (const h8*)hr_h, edges, offs, maxden, n);
    agg_kernel<<<(n + 3) / 4, 256, 0, stream>>>(xh, edges, offs, maxden, out, n);
}

// Round 5
// 354.696 us; speedup vs baseline: 2.1372x; 1.3009x over previous
//
#include <hip/hip_runtime.h>
#include <hip/hip_fp16.h>

#define HID 128

struct h8 { __half2 a, b, c, d; };   // 16 B = 8 halves
struct h4 { __half2 x, y; };         // 8 B = 4 halves

// ---------------- Fused prep: hist (bid%3==0) || x->fp16 (else) ----------------
__global__ __launch_bounds__(512) void prep_kernel(
    const float* __restrict__ x, h8* __restrict__ xh,
    const int* __restrict__ dst, int* __restrict__ counts,
    int ntot /* n*16 */, int e)
{
    int bid = blockIdx.x;
    int t   = threadIdx.x;
    if (bid % 3 == 0) {
        // histogram: 1024 edges per block, 2 per thread (strided, coalesced)
        int base = (bid / 3) * 1024;
        int i0 = base + t, i1 = i0 + 512;
        int d0 = (i0 < e) ? dst[i0] : -1;
        int d1 = (i1 < e) ? dst[i1] : -1;
        if (d0 >= 0) atomicAdd(&counts[d0], 1);
        if (d1 >= 0) atomicAdd(&counts[d1], 1);
    } else {
        // x -> fp16 rows: one h8 (8 floats) per thread
        int xb = (bid / 3) * 2 + (bid % 3) - 1;      // 0..3126
        int i  = xb * 512 + t;
        if (i < ntot) {
            const float4* p = (const float4*)x + (size_t)i * 2;
            float4 v0 = p[0], v1 = p[1];
            h8 o;
            o.a = __float22half2_rn(make_float2(v0.x, v0.y));
            o.b = __float22half2_rn(make_float2(v0.z, v0.w));
            o.c = __float22half2_rn(make_float2(v1.x, v1.y));
            o.d = __float22half2_rn(make_float2(v1.z, v1.w));
            xh[i] = o;
        }
    }
}

// ---------------- CSR scans ----------------
__global__ __launch_bounds__(512) void scan1_kernel(
    const int* __restrict__ counts, int* __restrict__ offs,
    int* __restrict__ bsums, int n)
{
    __shared__ int s[512];
    int tid = threadIdx.x;
    int i   = blockIdx.x * 512 + tid;
    int v   = (i < n) ? counts[i] : 0;
    s[tid] = v;
    __syncthreads();
    #pragma unroll
    for (int off = 1; off < 512; off <<= 1) {
        int add = (tid >= off) ? s[tid - off] : 0;
        __syncthreads();
        s[tid] += add;
        __syncthreads();
    }
    if (i < n) offs[i] = s[tid] - v;
    if (tid == 511) bsums[blockIdx.x] = s[511];
}

__global__ __launch_bounds__(512) void scan2_kernel(
    const int* __restrict__ bsums, int* __restrict__ bpref, int nb)
{
    __shared__ int s[512];
    int tid = threadIdx.x;
    int v   = (tid < nb) ? bsums[tid] : 0;
    s[tid] = v;
    __syncthreads();
    #pragma unroll
    for (int off = 1; off < 512; off <<= 1) {
        int add = (tid >= off) ? s[tid - off] : 0;
        __syncthreads();
        s[tid] += add;
        __syncthreads();
    }
    if (tid < nb) bpref[tid] = s[tid] - v;
}

// scan3 (finalize offs, seed cursor) || W pre-transpose, region-split grid.
__global__ __launch_bounds__(256) void scan3t_kernel(
    int* __restrict__ offs, const int* __restrict__ bpref,
    int* __restrict__ cursor, int n, int e, int nblk_scan,
    const float* __restrict__ Wl, const float* __restrict__ Wr,
    float* __restrict__ Wlt, float* __restrict__ Wrt)
{
    int bid = blockIdx.x;
    if (bid < nblk_scan) {
        int i = bid * 256 + threadIdx.x;
        if (i < n) {
            int v = offs[i] + bpref[i >> 9];
            offs[i]   = v;
            cursor[i] = v;
        }
        if (i == 0) offs[n] = e;
    } else {
        int i = (bid - nblk_scan) * 256 + threadIdx.x;   // 0..32767
        const float* in = (i < 16384) ? Wl : Wr;
        float* outp     = (i < 16384) ? Wlt : Wrt;
        int ii = i & 16383;
        int j = ii >> 7, k = ii & 127;
        outp[k * HID + j] = in[j * HID + k];
    }
}

// ---------------- Fused GEMM (bid%3 != 2) || scatter (bid%3 == 2) -------------
// GEMM: H = X @ W^T, fp32 math, fp16 rows out; 64x128 tile, 512 threads.
// Scatter: (src, alpha) records into dst-grouped order, 2-edge ILP.
__global__ __launch_bounds__(512) void gemm_scatter_kernel(
    const float* __restrict__ X, const float* __restrict__ Wlt,
    const float* __restrict__ Wrt, __half* __restrict__ Hl,
    __half* __restrict__ Hr, int n, int nblk_g /* blocks per matrix */,
    const int* __restrict__ dst, const int* __restrict__ src,
    const float* __restrict__ alpha, int* __restrict__ cursor,
    int2* __restrict__ edges, int e)
{
    int bid = blockIdx.x;
    int t   = threadIdx.x;

    if (bid % 3 == 2) {
        // ---------- scatter: 1024 edges per block ----------
        int base = (bid / 3) * 1024;
        int i0 = base + t, i1 = i0 + 512;
        int d0 = (i0 < e) ? dst[i0] : -1;
        int d1 = (i1 < e) ? dst[i1] : -1;
        int s0 = 0, s1 = 0; float a0 = 0.f, a1 = 0.f;
        if (d0 >= 0) { s0 = src[i0]; a0 = alpha[i0]; }
        if (d1 >= 0) { s1 = src[i1]; a1 = alpha[i1]; }
        int p0 = (d0 >= 0) ? atomicAdd(&cursor[d0], 1) : 0;
        int p1 = (d1 >= 0) ? atomicAdd(&cursor[d1], 1) : 0;
        if (d0 >= 0) edges[p0] = make_int2(s0, __float_as_int(a0));
        if (d1 >= 0) edges[p1] = make_int2(s1, __float_as_int(a1));
        return;
    }

    // ---------- GEMM ----------
    int g  = (bid / 3) * 2 + (bid % 3);    // 0 .. 2*nblk_g-1
    int by = (g >= nblk_g) ? 1 : 0;
    int bx = g - by * nblk_g;

    const float* __restrict__ Wt_g = by ? Wrt : Wlt;
    __half* __restrict__ H         = by ? Hr : Hl;

    __shared__ float Wt[64][HID];
    __shared__ float Xs[64][HID];

    const int row0 = bx * 64;

    #pragma unroll
    for (int rep = 0; rep < 4; ++rep) {
        int idx = rep * 512 + t;
        int r = idx >> 5, k0 = (idx & 31) << 2;
        int gr = row0 + r;
        float4 v = make_float4(0.f, 0.f, 0.f, 0.f);
        if (gr < n) v = *(const float4*)(X + (size_t)gr * HID + k0);
        *(float4*)&Xs[r][k0] = v;
    }

    const int tr = (t >> 5) << 2;
    const int tc = (t & 31) << 2;
    float acc[4][4];
    #pragma unroll
    for (int i = 0; i < 4; ++i)
        #pragma unroll
        for (int j = 0; j < 4; ++j) acc[i][j] = 0.f;

    for (int kh = 0; kh < 2; ++kh) {
        __syncthreads();
        #pragma unroll
        for (int rep = 0; rep < 4; ++rep) {
            int idx = rep * 512 + t;
            int k = idx >> 5, j0 = (idx & 31) << 2;
            *(float4*)&Wt[k][j0] =
                *(const float4*)(Wt_g + (size_t)((kh << 6) + k) * HID + j0);
        }
        __syncthreads();

        #pragma unroll 4
        for (int k4 = 0; k4 < 16; ++k4) {
            const int kl = k4 << 2;
            const int kg = (kh << 6) + kl;
            float4 xv[4];
            float4 wv[4];
            #pragma unroll
            for (int i = 0; i < 4; ++i)
                xv[i] = *(const float4*)&Xs[tr + i][kg];
            #pragma unroll
            for (int kk = 0; kk < 4; ++kk)
                wv[kk] = *(const float4*)&Wt[kl + kk][tc];
            #pragma unroll
            for (int i = 0; i < 4; ++i) {
                const float* xi = (const float*)&xv[i];
                #pragma unroll
                for (int kk = 0; kk < 4; ++kk) {
                    acc[i][0] = fmaf(xi[kk], wv[kk].x, acc[i][0]);
                    acc[i][1] = fmaf(xi[kk], wv[kk].y, acc[i][1]);
                    acc[i][2] = fmaf(xi[kk], wv[kk].z, acc[i][2]);
                    acc[i][3] = fmaf(xi[kk], wv[kk].w, acc[i][3]);
                }
            }
        }
    }

    #pragma unroll
    for (int i = 0; i < 4; ++i) {
        int gr = row0 + tr + i;
        if (gr < n) {
            h4 hv;
            hv.x = __float22half2_rn(make_float2(acc[i][0], acc[i][1]));
            hv.y = __float22half2_rn(make_float2(acc[i][2], acc[i][3]));
            *(h4*)(H + (size_t)gr * HID + tc) = hv;
        }
    }
}

// ---------------- Pass 1: per-edge scores + online (max, denom) per node ----
__global__ __launch_bounds__(256) void score_kernel(
    const h8* __restrict__ hl, const h8* __restrict__ hr,
    int2* __restrict__ edges, const int* __restrict__ offs,
    float2* __restrict__ maxdenom, int n)
{
    int node = blockIdx.x * 4 + (threadIdx.x >> 6);
    if (node >= n) return;
    int lane = threadIdx.x & 63;
    int sub  = lane >> 4;
    int sl   = lane & 15;

    int beg = offs[node];
    int end = offs[node + 1];
    if (beg == end) return;

    h8 hv = hr[(size_t)node * 16 + sl];
    float2 h0 = __half22float2(hv.a), h1 = __half22float2(hv.b);
    float2 h2 = __half22float2(hv.c), h3 = __half22float2(hv.d);

    int2 recA, recB; bool vA, vB;
    h8 rowA;
    {
        int ei = beg + sub;
        vA = ei < end;
        recA = vA ? edges[ei] : make_int2(0, 0);
    }
    rowA = hl[(size_t)recA.x * 16 + sl];
    {
        int ei = beg + 4 + sub;
        vB = ei < end;
        recB = vB ? edges[ei] : make_int2(0, 0);
    }

    float m = -3.0e38f, den = 0.f;
    for (int base = beg; base < end; base += 4) {
        h8 rowB;
        bool more = (base + 4) < end;
        if (more) rowB = hl[(size_t)recB.x * 16 + sl];
        int2 recC = make_int2(0, 0);
        bool vC = (base + 8 + sub) < end;
        if (vC) recC = edges[base + 8 + sub];

        float a = __int_as_float(recA.y);
        float p = 0.f, z;
        float2 t;
        t = __half22float2(rowA.a);
        z = (t.x + h0.x) * a; p += (z > 0.f ? z : 0.2f * z);
        z = (t.y + h0.y) * a; p += (z > 0.f ? z : 0.2f * z);
        t = __half22float2(rowA.b);
        z = (t.x + h1.x) * a; p += (z > 0.f ? z : 0.2f * z);
        z = (t.y + h1.y) * a; p += (z > 0.f ? z : 0.2f * z);
        t = __half22float2(rowA.c);
        z = (t.x + h2.x) * a; p += (z > 0.f ? z : 0.2f * z);
        z = (t.y + h2.y) * a; p += (z > 0.f ? z : 0.2f * z);
        t = __half22float2(rowA.d);
        z = (t.x + h3.x) * a; p += (z > 0.f ? z : 0.2f * z);
        z = (t.y + h3.y) * a; p += (z > 0.f ? z : 0.2f * z);
        p += __shfl_xor(p, 1);
        p += __shfl_xor(p, 2);
        p += __shfl_xor(p, 4);
        p += __shfl_xor(p, 8);
        if (!vA) p = -3.0e38f;
        if (vA && sl == 0) edges[base + sub].y = __float_as_int(p);

        float pm = fmaxf(p, __shfl_xor(p, 16));
        pm = fmaxf(pm, __shfl_xor(pm, 32));
        float mn = fmaxf(m, pm);
        float sc = __expf(m - mn);
        float w  = __expf(p - mn);
        den = den * sc + w;
        m = mn;

        recA = recB; vA = vB; rowA = rowB;
        recB = recC; vB = vC;
    }

    den += __shfl_xor(den, 16);
    den += __shfl_xor(den, 32);
    if (lane == 0) maxdenom[node] = make_float2(m, 1.f / den);
}

// ---------------- Pass 2: weighted aggregation ----------------
__global__ __launch_bounds__(256) void agg_kernel(
    const h8* __restrict__ xh, const int2* __restrict__ edges,
    const int* __restrict__ offs, const float2* __restrict__ maxdenom,
    float* __restrict__ out, int n)
{
    int node = blockIdx.x * 4 + (threadIdx.x >> 6);
    if (node >= n) return;
    int lane = threadIdx.x & 63;
    int sub  = lane >> 4;
    int sl   = lane & 15;

    float* orow = out + (size_t)node * HID + (sl << 3);
    int beg = offs[node];
    int end = offs[node + 1];
    if (beg == end) {
        if (sub == 0) {
            *(float4*)orow       = make_float4(0.f, 0.f, 0.f, 0.f);
            *(float4*)(orow + 4) = make_float4(0.f, 0.f, 0.f, 0.f);
        }
        return;
    }

    float2 md = maxdenom[node];
    const float m = md.x, inv = md.y;

    int2 recA, recB; bool vA, vB;
    h8 rowA;
    {
        int ei = beg + sub;
        vA = ei < end;
        recA = vA ? edges[ei] : make_int2(0, 0);
    }
    rowA = xh[(size_t)recA.x * 16 + sl];
    {
        int ei = beg + 4 + sub;
        vB = ei < end;
        recB = vB ? edges[ei] : make_int2(0, 0);
    }

    float4 aca = make_float4(0.f, 0.f, 0.f, 0.f);
    float4 acb = make_float4(0.f, 0.f, 0.f, 0.f);

    for (int base = beg; base < end; base += 4) {
        h8 rowB;
        bool more = (base + 4) < end;
        if (more) rowB = xh[(size_t)recB.x * 16 + sl];
        int2 recC = make_int2(0, 0);
        bool vC = (base + 8 + sub) < end;
        if (vC) recC = edges[base + 8 + sub];

        float w = vA ? __expf(__int_as_float(recA.y) - m) * inv : 0.f;
        float2 t;
        t = __half22float2(rowA.a);
        aca.x = fmaf(w, t.x, aca.x); aca.y = fmaf(w, t.y, aca.y);
        t = __half22float2(rowA.b);
        aca.z = fmaf(w, t.x, aca.z); aca.w = fmaf(w, t.y, aca.w);
        t = __half22float2(rowA.c);
        acb.x = fmaf(w, t.x, acb.x); acb.y = fmaf(w, t.y, acb.y);
        t = __half22float2(rowA.d);
        acb.z = fmaf(w, t.x, acb.z); acb.w = fmaf(w, t.y, acb.w);

        recA = recB; vA = vB; rowA = rowB;
        recB = recC; vB = vC;
    }

    aca.x += __shfl_xor(aca.x, 16); aca.x += __shfl_xor(aca.x, 32);
    aca.y += __shfl_xor(aca.y, 16); aca.y += __shfl_xor(aca.y, 32);
    aca.z += __shfl_xor(aca.z, 16); aca.z += __shfl_xor(aca.z, 32);
    aca.w += __shfl_xor(aca.w, 16); aca.w += __shfl_xor(aca.w, 32);
    acb.x += __shfl_xor(acb.x, 16); acb.x += __shfl_xor(acb.x, 32);
    acb.y += __shfl_xor(acb.y, 16); acb.y += __shfl_xor(acb.y, 32);
    acb.z += __shfl_xor(acb.z, 16); acb.z += __shfl_xor(acb.z, 32);
    acb.w += __shfl_xor(acb.w, 16); acb.w += __shfl_xor(acb.w, 32);

    if (sub == 0) {
        *(float4*)orow       = aca;
        *(float4*)(orow + 4) = acb;
    }
}

// ---------------- launcher ----------------
extern "C" void kernel_launch(void* const* d_in, const int* in_sizes, int n_in,
                              void* d_out, int out_size, void* d_ws, size_t ws_size,
                              hipStream_t stream)
{
    const float* x     = (const float*)d_in[0];
    const float* Wl    = (const float*)d_in[1];
    const float* Wr    = (const float*)d_in[2];
    const float* alpha = (const float*)d_in[3];
    const int*   src   = (const int*)d_in[4];
    const int*   dst   = (const int*)d_in[5];
    const int n = in_sizes[0] / HID;   // 100000 nodes
    const int e = in_sizes[4];         // 1600000 edges
    float* out = (float*)d_out;

    char* ws = (char*)d_ws;
    size_t off = 0;
    auto carve = [&](size_t bytes) -> void* {
        void* p = ws + off;
        off = (off + bytes + 255) & ~(size_t)255;
        return p;
    };
    __half* hl_h    = (__half*)carve((size_t)n * HID * sizeof(__half));
    __half* hr_h    = (__half*)carve((size_t)n * HID * sizeof(__half));
    h8*     xh      = (h8*)carve((size_t)n * HID * sizeof(__half));
    int*    offs    = (int*)carve((size_t)(n + 1) * sizeof(int));
    int*    counts  = (int*)carve((size_t)n * sizeof(int));
    int*    cursor  = (int*)carve((size_t)n * sizeof(int));
    int*    bsums   = (int*)carve(512 * sizeof(int));
    int*    bpref   = (int*)carve(512 * sizeof(int));
    int2*   edges   = (int2*)carve((size_t)e * sizeof(int2));
    float2* maxden  = (float2*)carve((size_t)n * sizeof(float2));
    float*  Wlt     = (float*)carve((size_t)HID * HID * sizeof(float));
    float*  Wrt     = (float*)carve((size_t)HID * HID * sizeof(float));

    hipMemsetAsync(counts, 0, (size_t)n * sizeof(int), stream);

    // 1) prep: hist || x->fp16   (grid = 3 * blocks-per-region)
    int nblk_e = (e + 1023) / 1024;            // 1563 (hist & scatter regions)
    prep_kernel<<<3 * nblk_e, 512, 0, stream>>>(x, xh, dst, counts, n * 16, e);

    // 2) scans (+ W transpose appended to scan3's grid)
    int nb = (n + 511) / 512;                  // 196
    scan1_kernel<<<nb, 512, 0, stream>>>(counts, offs, bsums, n);
    scan2_kernel<<<1, 512, 0, stream>>>(bsums, bpref, nb);
    int nblk_s3 = (n + 255) / 256;             // 391
    scan3t_kernel<<<nblk_s3 + 128, 256, 0, stream>>>(offs, bpref, cursor, n, e,
                                                     nblk_s3, Wl, Wr, Wlt, Wrt);

    // 3) fused gemm || scatter  (grid = 3 * 1563: 2/3 gemm, 1/3 scatter)
    int nblk_g = (n + 63) / 64;                // 1563 blocks per matrix
    gemm_scatter_kernel<<<3 * nblk_g, 512, 0, stream>>>(
        x, Wlt, Wrt, hl_h, hr_h, n, nblk_g,
        dst, src, alpha, cursor, edges, e);

    // 4) pass 1: scores + (max, 1/denom); pass 2: weighted aggregation
    score_kernel<<<(n + 3) / 4, 256, 0, stream>>>(
        (const h8*)hl_h, (const h8*)hr_h, edges, offs, maxden, n);
    agg_kernel<<<(n + 3) / 4, 256, 0, stream>>>(xh, edges, offs, maxden, out, n);
}